// Round 8
// baseline (135.859 us; speedup 1.0000x reference)
//
#include <hip/hip_runtime.h>
#include <math.h>

#define NHEAD 8
#define DIM   32
#define TOPK  8
#define TEMP  0.17677669529663687f   // 1/sqrt(32)
#define BATCH 4

// Butterfly argmax over 32 lanes, tie-break: lowest index (matches jax.lax.top_k)
__device__ __forceinline__ void argmax32(float& v, int& i) {
#pragma unroll
  for (int off = 16; off >= 1; off >>= 1) {
    float ov = __shfl_xor(v, off, 32);
    int   oi = __shfl_xor(i, off, 32);
    if (ov > v || (ov == v && oi < i)) { v = ov; i = oi; }
  }
}

// ---------------- Fused transpose: levels 0/1 Q,K,V -> token-major ---------
// [B, 256, S] -> [B, S, 256]. Flat grid of 32x32 tiles: 3072 (lvl1) + 12288 (lvl0).
__global__ __launch_bounds__(256) void transpose_all(
    const float* __restrict__ Q1, const float* __restrict__ K1, const float* __restrict__ V1,
    float* __restrict__ Qt1, float* __restrict__ Kt1, float* __restrict__ Vt1,
    const float* __restrict__ Q0, const float* __restrict__ K0, const float* __restrict__ V0,
    float* __restrict__ Qt0, float* __restrict__ Kt0, float* __restrict__ Vt0)
{
  __shared__ float tile[32][36];
  int id = blockIdx.x;
  const float* in; float* out; int S, b, t;
  if (id < 3072) {                      // level1 Q,K,V
    S = 1024;
    const int tsel = id >> 10;
    in  = tsel == 0 ? Q1 : tsel == 1 ? K1 : V1;
    out = tsel == 0 ? Qt1 : tsel == 1 ? Kt1 : Vt1;
    b = (id >> 8) & 3; t = id & 255;
  } else {                              // level0 Q,K,V
    id -= 3072; S = 4096;
    const int tsel = id >> 12;
    in  = tsel == 0 ? Q0 : tsel == 1 ? K0 : V0;
    out = tsel == 0 ? Qt0 : tsel == 1 ? Kt0 : Vt0;
    b = (id >> 10) & 3; t = id & 1023;
  }
  const int sx = t / 8, cy = t % 8;
  const int s0 = sx * 32, c0 = cy * 32;
  const int tid = threadIdx.x;
  const int i = tid >> 3, c4 = tid & 7;

  const float4 v4 = *(const float4*)(in + ((size_t)b * 256 + c0 + i) * S + s0 + c4 * 4);
  *(float4*)&tile[i][c4 * 4] = v4;
  __syncthreads();
  float4 w;
  w.x = tile[c4 * 4 + 0][i];
  w.y = tile[c4 * 4 + 1][i];
  w.z = tile[c4 * 4 + 2][i];
  w.w = tile[c4 * 4 + 3][i];
  *(float4*)(out + ((size_t)b * S + s0 + i) * 256 + c0 + c4 * 4) = w;
}

// ---------------- Level 0 v5: all channel-major, regs-only probs -----------
// grid: B*256 blocks, 256 threads = 8 heads x 32 lanes; lane owns s=lane*8+j
__global__ __launch_bounds__(256) void l0_kernel_v5(
    const float* __restrict__ Q, const float* __restrict__ K, const float* __restrict__ V,
    float* __restrict__ msg0, int* __restrict__ tki0, float* __restrict__ tkp0)
{
  const int b = blockIdx.x >> 8;
  const int l = blockIdx.x & 255;
  const int t = threadIdx.x;
  const int h = t >> 5, lane = t & 31;

  __shared__ float q_s[NHEAD][DIM];

  const size_t cb = ((size_t)(b * 256 + h * 32)) * 256;  // channel-major [b,c,s]

  q_s[h][lane] = Q[cb + (size_t)lane * 256 + l];
  // q_s per-head within one half-wave: no barrier needed

  float sc[8];
#pragma unroll
  for (int j = 0; j < 8; ++j) sc[j] = 0.f;
  const float* kbase = K + cb + lane * 8;
  for (int d = 0; d < 32; ++d) {
    const float4 ka = *(const float4*)(kbase + (size_t)d * 256);
    const float4 kb = *(const float4*)(kbase + (size_t)d * 256 + 4);
    const float qd = q_s[h][d];
    sc[0] += qd * ka.x; sc[1] += qd * ka.y; sc[2] += qd * ka.z; sc[3] += qd * ka.w;
    sc[4] += qd * kb.x; sc[5] += qd * kb.y; sc[6] += qd * kb.z; sc[7] += qd * kb.w;
  }
#pragma unroll
  for (int j = 0; j < 8; ++j) sc[j] *= TEMP;

  // softmax over all 256
  float mx = sc[0];
#pragma unroll
  for (int j = 1; j < 8; ++j) mx = fmaxf(mx, sc[j]);
#pragma unroll
  for (int off = 16; off >= 1; off >>= 1) mx = fmaxf(mx, __shfl_xor(mx, off, 32));
  float ev[8]; float ssum = 0.f;
#pragma unroll
  for (int j = 0; j < 8; ++j) { ev[j] = expf(sc[j] - mx); ssum += ev[j]; }
#pragma unroll
  for (int off = 16; off >= 1; off >>= 1) ssum += __shfl_xor(ssum, off, 32);
  const float inv = 1.f / ssum;

  // top-8 on scaled scores; global id gi = lane*8+j
  int msk = 0;
#pragma unroll
  for (int k = 0; k < TOPK; ++k) {
    float bv = -INFINITY; int bi = 1 << 30;
#pragma unroll
    for (int j = 0; j < 8; ++j) {
      if (!((msk >> j) & 1)) {
        const int gi = lane * 8 + j;
        if (sc[j] > bv || (sc[j] == bv && gi < bi)) { bv = sc[j]; bi = gi; }
      }
    }
    argmax32(bv, bi);
    if ((bi >> 3) == lane) msk |= 1 << (bi & 7);
    if (lane == k) {
      const int o = ((b * 256 + l) * TOPK + k) * NHEAD + h;
      tki0[o] = bi;
      tkp0[o] = expf(bv - mx) * inv;
    }
  }

  // masked probabilities stay in registers
  float p[8];
#pragma unroll
  for (int j = 0; j < 8; ++j) p[j] = ((msk >> j) & 1) ? 0.f : ev[j] * inv;

  // PV: per-dim partials with fully-coalesced float4 row reads (lane covers
  // its own 8 s-slots of each V row), then butterfly transpose-reduce.
  float red[32];
  const float* vb0 = V + cb + lane * 8;
#pragma unroll
  for (int d = 0; d < 32; ++d) {
    const float4 va = *(const float4*)(vb0 + (size_t)d * 256);
    const float4 vq = *(const float4*)(vb0 + (size_t)d * 256 + 4);
    red[d] = p[0] * va.x + p[1] * va.y + p[2] * va.z + p[3] * va.w
           + p[4] * vq.x + p[5] * vq.y + p[6] * vq.z + p[7] * vq.w;
  }
  // after this, lane d holds sum over lanes of red[d]
#pragma unroll
  for (int off = 16; off >= 1; off >>= 1) {
#pragma unroll
    for (int i = 0; i < off; ++i) {
      const float give = (lane & off) ? red[i] : red[i + off];
      const float got  = __shfl_xor(give, off, 32);
      red[i] = ((lane & off) ? red[i + off] : red[i]) + got;
    }
  }

  msg0[((size_t)(b * 256 + l) * NHEAD + h) * DIM + lane] = red[0];
}

// ---------------- Token-major refinement v3 + XCD-chunked swizzle ----------
// grid: B*(W/2)^2 blocks, 256 threads = 8 heads x 32 lanes (lane = entry e)
template <int W, bool HAS_TOPK>
__global__ __launch_bounds__(256) void refine_tm_kernel(
    const float* __restrict__ Qt, const float* __restrict__ Kt, const float* __restrict__ Vt,
    const float* __restrict__ msgp, const int* __restrict__ tkip, const float* __restrict__ tkpp,
    float* __restrict__ msgo, int* __restrict__ tkio, float* __restrict__ tkpo)
{
  constexpr int S  = W * W;
  constexpr int HW = W / 2;
  constexpr int Lp = HW * HW;
  constexpr int NWG = BATCH * Lp;      // % 8 == 0 -> bijective swizzle
  constexpr int PER = NWG / 8;
  const int bidx = (int)blockIdx.x;
  const int swz = (bidx & 7) * PER + (bidx >> 3);   // contiguous chunk per XCD
  const int b = swz / Lp;
  const int l = swz % Lp;
  const int gr = l / HW, gc = l % HW;
  const int t = threadIdx.x;
  const int h = t >> 5, lane = t & 31;

  __shared__ __align__(16) float q_s[NHEAD][4][DIM];
  __shared__ __align__(16) float w_s[NHEAD][32];
  __shared__ int cidx_s[NHEAD][32];

  const size_t tb = (size_t)b * S * 256;      // token-major [b,s,c]

  // entry e = lane: gathered child index + coarse score
  const int k0 = lane >> 2, f = lane & 3;
  const int pofs = ((b * Lp + l) * TOPK + k0) * NHEAD + h;
  const int ti = tkip[pofs];
  const float csc = tkpp[pofs];
  const int cidx = ((ti / HW) * 2 + (f >> 1)) * W + ((ti % HW) * 2 + (f & 1));
  cidx_s[h][lane] = cidx;
  // all LDS per-head within one half-wave (lockstep) -> no barriers

  // Q for the 4 fine children (coalesced)
#pragma unroll
  for (int wq = 0; wq < 4; ++wq) {
    const int rr = 2 * gr + (wq >> 1), cc = 2 * gc + (wq & 1);
    q_s[h][wq][lane] = Qt[tb + (size_t)(rr * W + cc) * 256 + h * DIM + lane];
  }

  const float mprev = msgp[((size_t)(b * Lp + l) * NHEAD + h) * DIM + lane];

  // K: per-lane float4 gather (lane = entry)
  float kv[DIM];
  {
    const float4* kp = (const float4*)(Kt + tb + (size_t)cidx * 256 + h * DIM);
#pragma unroll
    for (int j = 0; j < 8; ++j) {
      const float4 v4 = kp[j];
      kv[4 * j] = v4.x; kv[4 * j + 1] = v4.y; kv[4 * j + 2] = v4.z; kv[4 * j + 3] = v4.w;
    }
  }

  // V coalesced into registers: lane = dim, loop over entries
  float vv[32];
#pragma unroll
  for (int e = 0; e < 32; ++e)
    vv[e] = Vt[tb + (size_t)cidx_s[h][e] * 256 + h * DIM + lane];

  // qk for all 4 children (float4 broadcast reads of q_s)
  float qk4[4] = {0.f, 0.f, 0.f, 0.f};
#pragma unroll
  for (int d4 = 0; d4 < 8; ++d4) {
#pragma unroll
    for (int wq = 0; wq < 4; ++wq) {
      const float4 q4 = *(const float4*)&q_s[h][wq][d4 * 4];
      qk4[wq] += q4.x * kv[4 * d4] + q4.y * kv[4 * d4 + 1]
               + q4.z * kv[4 * d4 + 2] + q4.w * kv[4 * d4 + 3];
    }
  }

#pragma unroll
  for (int wq = 0; wq < 4; ++wq) {
    const float sval = TEMP * qk4[wq];

    // softmax over the 4 children (f groups of 4 lanes)
    float m1 = fmaxf(sval, __shfl_xor(sval, 1, 4));
    float m2 = fmaxf(m1, __shfl_xor(m1, 2, 4));
    float ex = expf(sval - m2);
    float s1 = ex + __shfl_xor(ex, 1, 4);
    float s2 = s1 + __shfl_xor(s1, 2, 4);
    const float A = (ex / s2) * csc;

    w_s[h][lane] = A;        // same-wave LDS ordering -> visible to reads below

    const int tok = (2 * gr + (wq >> 1)) * W + (2 * gc + (wq & 1));
    float acc = 0.f;

    if constexpr (HAS_TOPK) {
      // rank = # entries strictly ahead in jax.lax.top_k's stable descending order
      int rank = 0;
#pragma unroll
      for (int e4 = 0; e4 < 8; ++e4) {
        const float4 a4 = *(const float4*)&w_s[h][e4 * 4];
        rank += (a4.x > A || (a4.x == A && (e4 * 4 + 0) < lane));
        rank += (a4.y > A || (a4.y == A && (e4 * 4 + 1) < lane));
        rank += (a4.z > A || (a4.z == A && (e4 * 4 + 2) < lane));
        rank += (a4.w > A || (a4.w == A && (e4 * 4 + 3) < lane));
      }
      const unsigned long long bal = __ballot(rank < TOPK);
      const unsigned mbits = (unsigned)(bal >> (t & 32));  // this half-wave's 32 bits

      if (rank < TOPK) {
        const int o = ((b * S + tok) * TOPK + rank) * NHEAD + h;
        tkio[o] = cidx;
        tkpo[o] = A;
      }

      // PV with top-8 masked to zero (== reference's sum-minus-topk)
#pragma unroll
      for (int e4 = 0; e4 < 8; ++e4) {
        const float4 a4 = *(const float4*)&w_s[h][e4 * 4];
        acc += (((mbits >> (e4 * 4 + 0)) & 1) ? 0.f : a4.x) * vv[e4 * 4 + 0];
        acc += (((mbits >> (e4 * 4 + 1)) & 1) ? 0.f : a4.y) * vv[e4 * 4 + 1];
        acc += (((mbits >> (e4 * 4 + 2)) & 1) ? 0.f : a4.z) * vv[e4 * 4 + 2];
        acc += (((mbits >> (e4 * 4 + 3)) & 1) ? 0.f : a4.w) * vv[e4 * 4 + 3];
      }
    } else {
      // final level: plain weighted sum, no mask, no rank
#pragma unroll
      for (int e4 = 0; e4 < 8; ++e4) {
        const float4 a4 = *(const float4*)&w_s[h][e4 * 4];
        acc += a4.x * vv[e4 * 4 + 0];
        acc += a4.y * vv[e4 * 4 + 1];
        acc += a4.z * vv[e4 * 4 + 2];
        acc += a4.w * vv[e4 * 4 + 3];
      }
    }

    msgo[((size_t)(b * S + tok) * NHEAD + h) * DIM + lane] = mprev + acc;
  }
}

// ---------------- Fallback path (channel-major, small workspace) -----------
__global__ __launch_bounds__(256) void l0_cm_kernel(
    const float* __restrict__ Q, const float* __restrict__ K, const float* __restrict__ V,
    float* __restrict__ msg0, int* __restrict__ tki0, float* __restrict__ tkp0)
{
  const int b = blockIdx.x >> 8;
  const int l = blockIdx.x & 255;
  const int t = threadIdx.x;
  const int h = t >> 5, lane = t & 31;

  __shared__ float q_s[NHEAD][DIM];
  __shared__ float probs[NHEAD][256];

  const size_t cb = ((size_t)(b * 256 + h * 32)) * 256;
  q_s[h][lane] = Q[cb + (size_t)lane * 256 + l];

  float sc[8];
#pragma unroll
  for (int j = 0; j < 8; ++j) sc[j] = 0.f;
  for (int d = 0; d < 32; ++d) {
    const float qd = q_s[h][d];
    const float* kr = K + cb + (size_t)d * 256;
#pragma unroll
    for (int j = 0; j < 8; ++j) sc[j] += qd * kr[j * 32 + lane];
  }
#pragma unroll
  for (int j = 0; j < 8; ++j) sc[j] *= TEMP;

  float mx = sc[0];
#pragma unroll
  for (int j = 1; j < 8; ++j) mx = fmaxf(mx, sc[j]);
#pragma unroll
  for (int off = 16; off >= 1; off >>= 1) mx = fmaxf(mx, __shfl_xor(mx, off, 32));
  float ev[8]; float ssum = 0.f;
#pragma unroll
  for (int j = 0; j < 8; ++j) { ev[j] = expf(sc[j] - mx); ssum += ev[j]; }
#pragma unroll
  for (int off = 16; off >= 1; off >>= 1) ssum += __shfl_xor(ssum, off, 32);
  const float inv = 1.f / ssum;

  int msk = 0;
#pragma unroll
  for (int k = 0; k < TOPK; ++k) {
    float bv = -INFINITY; int bi = 1 << 30;
#pragma unroll
    for (int j = 0; j < 8; ++j) {
      if (!((msk >> j) & 1)) {
        int gi = j * 32 + lane;
        if (sc[j] > bv || (sc[j] == bv && gi < bi)) { bv = sc[j]; bi = gi; }
      }
    }
    argmax32(bv, bi);
    if ((bi & 31) == lane) msk |= 1 << (bi >> 5);
    if (lane == k) {
      const int o = ((b * 256 + l) * TOPK + k) * NHEAD + h;
      tki0[o] = bi;
      tkp0[o] = expf(bv - mx) * inv;
    }
  }

#pragma unroll
  for (int j = 0; j < 8; ++j)
    probs[h][j * 32 + lane] = ((msk >> j) & 1) ? 0.f : ev[j] * inv;
  __syncthreads();

  float acc = 0.f;
  const float* vr = V + cb + (size_t)lane * 256;
  for (int s = 0; s < 256; ++s) acc += probs[h][s] * vr[s];

  msg0[((size_t)(b * 256 + l) * NHEAD + h) * DIM + lane] = acc;
}

template <int W, bool HAS_TOPK>
__global__ __launch_bounds__(256) void refine_cm_kernel(
    const float* __restrict__ Q, const float* __restrict__ K, const float* __restrict__ V,
    const float* __restrict__ msgp, const int* __restrict__ tkip, const float* __restrict__ tkpp,
    float* __restrict__ msgo, int* __restrict__ tkio, float* __restrict__ tkpo)
{
  constexpr int S  = W * W;
  constexpr int HW = W / 2;
  constexpr int Lp = HW * HW;
  const int b = blockIdx.x / Lp;
  const int l = blockIdx.x % Lp;
  const int gr = l / HW, gc = l % HW;
  const int t = threadIdx.x;
  const int h = t >> 5, lane = t & 31;

  __shared__ float q_s[4][NHEAD][DIM];
  __shared__ int   cidx_s[NHEAD][32];
  __shared__ float w_s[NHEAD][32];

  const size_t cbase = ((size_t)(b * 256 + h * 32)) * S;

#pragma unroll
  for (int wq = 0; wq < 4; ++wq) {
    const int rr = 2 * gr + (wq >> 1), cc = 2 * gc + (wq & 1);
    q_s[wq][h][lane] = Q[cbase + (size_t)lane * S + rr * W + cc];
  }

  const int k0 = lane >> 2, f = lane & 3;
  const int pofs = ((b * Lp + l) * TOPK + k0) * NHEAD + h;
  const int ti = tkip[pofs];
  const float csc = tkpp[pofs];
  cidx_s[h][lane] = ((ti / HW) * 2 + (f >> 1)) * W + ((ti % HW) * 2 + (f & 1));
  const int cidx = cidx_s[h][lane];

  float kv[DIM];
#pragma unroll
  for (int d = 0; d < DIM; ++d) kv[d] = K[cbase + (size_t)d * S + cidx];

  const float mprev = msgp[((size_t)(b * Lp + l) * NHEAD + h) * DIM + lane];

  for (int wq = 0; wq < 4; ++wq) {
    float qk = 0.f;
#pragma unroll
    for (int d = 0; d < DIM; ++d) qk += q_s[wq][h][d] * kv[d];
    const float v = TEMP * qk;

    float m1 = fmaxf(v, __shfl_xor(v, 1, 4));
    float m2 = fmaxf(m1, __shfl_xor(m1, 2, 4));
    float ex = expf(v - m2);
    float s1 = ex + __shfl_xor(ex, 1, 4);
    float s2 = s1 + __shfl_xor(s1, 2, 4);
    const float A = (ex / s2) * csc;

    float Am = A;
    int   my_e = 0; float my_v = 0.f;
    if constexpr (HAS_TOPK) {
      bool mymask = false;
#pragma unroll
      for (int k = 0; k < TOPK; ++k) {
        float bv = mymask ? -INFINITY : A;
        int bi = lane;
        argmax32(bv, bi);
        if (bi == lane) mymask = true;
        if (lane == k) { my_e = bi; my_v = bv; }
      }
      if (mymask) Am = 0.f;
    }

    w_s[h][lane] = Am;

    float acc = 0.f;
    const float* vcol = V + cbase + (size_t)lane * S;
#pragma unroll
    for (int e = 0; e < 32; ++e) acc += w_s[h][e] * vcol[cidx_s[h][e]];
    const float outv = mprev + acc;

    const int rr = 2 * gr + (wq >> 1), cc = 2 * gc + (wq & 1);
    const int tok = rr * W + cc;
    msgo[((size_t)(b * S + tok) * NHEAD + h) * DIM + lane] = outv;
    if constexpr (HAS_TOPK) {
      if (lane < TOPK) {
        const int o = ((b * S + tok) * TOPK + lane) * NHEAD + h;
        tkio[o] = cidx_s[h][my_e];
        tkpo[o] = my_v;
      }
    }
  }
}

extern "C" void kernel_launch(void* const* d_in, const int* in_sizes, int n_in,
                              void* d_out, int out_size, void* d_ws, size_t ws_size,
                              hipStream_t stream)
{
  const float* Q0 = (const float*)d_in[0];  // 64x64 (fine)
  const float* Q1 = (const float*)d_in[1];  // 32x32
  const float* Q2 = (const float*)d_in[2];  // 16x16 (coarse)
  const float* K0 = (const float*)d_in[3];
  const float* K1 = (const float*)d_in[4];
  const float* K2 = (const float*)d_in[5];
  const float* V0 = (const float*)d_in[6];
  const float* V1 = (const float*)d_in[7];
  const float* V2 = (const float*)d_in[8];
  float* out = (float*)d_out;

  const size_t N_MSG0 = (size_t)BATCH * 256 * NHEAD * DIM;
  const size_t N_TK0  = (size_t)BATCH * 256 * TOPK * NHEAD;
  const size_t N_MSG1 = (size_t)BATCH * 1024 * NHEAD * DIM;
  const size_t N_TK1  = (size_t)BATCH * 1024 * TOPK * NHEAD;
  const size_t N_T1   = (size_t)BATCH * 1024 * 256;
  const size_t N_T0   = (size_t)BATCH * 4096 * 256;

  float* p = (float*)d_ws;
  float* msg0 = p;            p += N_MSG0;
  int*   tki0 = (int*)p;      p += N_TK0;
  float* tkp0 = p;            p += N_TK0;
  float* msg1 = p;            p += N_MSG1;
  int*   tki1 = (int*)p;      p += N_TK1;
  float* tkp1 = p;            p += N_TK1;
  float* Qt1  = p;            p += N_T1;
  float* Kt1  = p;            p += N_T1;
  float* Vt1  = p;            p += N_T1;
  float* Qt0  = p;            p += N_T0;
  float* Kt0  = p;            p += N_T0;
  float* Vt0  = p;            p += N_T0;
  const size_t need_bytes = (size_t)(p - (float*)d_ws) * sizeof(float);

  if (ws_size >= need_bytes) {
    hipLaunchKernelGGL(l0_kernel_v5, dim3(BATCH * 256), dim3(256), 0, stream,
                       Q2, K2, V2, msg0, tki0, tkp0);
    hipLaunchKernelGGL(transpose_all, dim3(3072 + 12288), dim3(256), 0, stream,
                       Q1, K1, V1, Qt1, Kt1, Vt1, Q0, K0, V0, Qt0, Kt0, Vt0);
    hipLaunchKernelGGL((refine_tm_kernel<32, true>), dim3(BATCH * 256), dim3(256), 0, stream,
                       Qt1, Kt1, Vt1, msg0, tki0, tkp0, msg1, tki1, tkp1);
    hipLaunchKernelGGL((refine_tm_kernel<64, false>), dim3(BATCH * 1024), dim3(256), 0, stream,
                       Qt0, Kt0, Vt0, msg1, tki1, tkp1, out, nullptr, nullptr);
  } else {
    hipLaunchKernelGGL(l0_cm_kernel, dim3(BATCH * 256), dim3(256), 0, stream,
                       Q2, K2, V2, msg0, tki0, tkp0);
    hipLaunchKernelGGL((refine_cm_kernel<32, true>), dim3(BATCH * 256), dim3(256), 0, stream,
                       Q1, K1, V1, msg0, tki0, tkp0, msg1, tki1, tkp1);
    hipLaunchKernelGGL((refine_cm_kernel<64, false>), dim3(BATCH * 1024), dim3(256), 0, stream,
                       Q0, K0, V0, msg1, tki1, tkp1, out, nullptr, nullptr);
  }
}

// Round 9
// 115.078 us; speedup vs baseline: 1.1806x; 1.1806x over previous
//
#include <hip/hip_runtime.h>
#include <math.h>

#define NHEAD 8
#define DIM   32
#define TOPK  8
#define TEMP  0.17677669529663687f   // 1/sqrt(32)
#define BATCH 4

// Butterfly argmax over 32 lanes, tie-break: lowest index (matches jax.lax.top_k)
__device__ __forceinline__ void argmax32(float& v, int& i) {
#pragma unroll
  for (int off = 16; off >= 1; off >>= 1) {
    float ov = __shfl_xor(v, off, 32);
    int   oi = __shfl_xor(i, off, 32);
    if (ov > v || (ov == v && oi < i)) { v = ov; i = oi; }
  }
}

// ---------------- Fused transpose: all levels/tensors, one launch ----------
// [B, 256, S] -> [B, S, 256]. Flat grid of 32x32 tiles:
//  job V2 (S=256): 256 tiles; Q1,K1,V1 (S=1024): 3072; Q0,K0,V0 (S=4096): 12288.
__global__ __launch_bounds__(256) void transpose_all(
    const float* __restrict__ V2, float* __restrict__ Vt2,
    const float* __restrict__ Q1, const float* __restrict__ K1, const float* __restrict__ V1,
    float* __restrict__ Qt1, float* __restrict__ Kt1, float* __restrict__ Vt1,
    const float* __restrict__ Q0, const float* __restrict__ K0, const float* __restrict__ V0,
    float* __restrict__ Qt0, float* __restrict__ Kt0, float* __restrict__ Vt0)
{
  __shared__ float tile[32][36];
  int id = blockIdx.x;
  const float* in; float* out; int S, b, t;
  if (id < 256) {                       // level2 V only
    S = 256; in = V2; out = Vt2;
    b = id >> 6; t = id & 63;
  } else if (id < 256 + 3072) {         // level1 Q,K,V
    id -= 256; S = 1024;
    const int tsel = id >> 10;
    in  = tsel == 0 ? Q1 : tsel == 1 ? K1 : V1;
    out = tsel == 0 ? Qt1 : tsel == 1 ? Kt1 : Vt1;
    b = (id >> 8) & 3; t = id & 255;
  } else {                              // level0 Q,K,V
    id -= 256 + 3072; S = 4096;
    const int tsel = id >> 12;
    in  = tsel == 0 ? Q0 : tsel == 1 ? K0 : V0;
    out = tsel == 0 ? Qt0 : tsel == 1 ? Kt0 : Vt0;
    b = (id >> 10) & 3; t = id & 1023;
  }
  const int sx = t / 8, cy = t % 8;
  const int s0 = sx * 32, c0 = cy * 32;
  const int tid = threadIdx.x;
  const int i = tid >> 3, c4 = tid & 7;

  const float4 v4 = *(const float4*)(in + ((size_t)b * 256 + c0 + i) * S + s0 + c4 * 4);
  *(float4*)&tile[i][c4 * 4] = v4;
  __syncthreads();
  float4 w;
  w.x = tile[c4 * 4 + 0][i];
  w.y = tile[c4 * 4 + 1][i];
  w.z = tile[c4 * 4 + 2][i];
  w.w = tile[c4 * 4 + 3][i];
  *(float4*)(out + ((size_t)b * S + s0 + i) * 256 + c0 + c4 * 4) = w;
}

// ---------------- Level 0 v4 (proven): float4 K, LDS probs, token-major V --
// grid: B*256 blocks, 256 threads = 8 heads x 32 lanes; lane owns s=lane*8+j
__global__ __launch_bounds__(256) void l0_kernel_v4(
    const float* __restrict__ Q, const float* __restrict__ K, const float* __restrict__ Vt,
    float* __restrict__ msg0, int* __restrict__ tki0, float* __restrict__ tkp0)
{
  const int b = blockIdx.x >> 8;
  const int l = blockIdx.x & 255;
  const int t = threadIdx.x;
  const int h = t >> 5, lane = t & 31;

  __shared__ float q_s[NHEAD][DIM];
  __shared__ float probs[NHEAD][256];   // slot j*32+lane holds s = lane*8+j

  const size_t cb = ((size_t)(b * 256 + h * 32)) * 256;  // channel-major [b,c,s]
  const size_t tb = (size_t)b * 256 * 256;               // token-major [b,s,c]

  q_s[h][lane] = Q[cb + (size_t)lane * 256 + l];
  // all LDS per-head within one half-wave: no barriers needed

  float sc[8];
#pragma unroll
  for (int j = 0; j < 8; ++j) sc[j] = 0.f;
  const float* kbase = K + cb + lane * 8;
  for (int d = 0; d < 32; ++d) {
    const float4 ka = *(const float4*)(kbase + (size_t)d * 256);
    const float4 kb = *(const float4*)(kbase + (size_t)d * 256 + 4);
    const float qd = q_s[h][d];
    sc[0] += qd * ka.x; sc[1] += qd * ka.y; sc[2] += qd * ka.z; sc[3] += qd * ka.w;
    sc[4] += qd * kb.x; sc[5] += qd * kb.y; sc[6] += qd * kb.z; sc[7] += qd * kb.w;
  }
#pragma unroll
  for (int j = 0; j < 8; ++j) sc[j] *= TEMP;

  float mx = sc[0];
#pragma unroll
  for (int j = 1; j < 8; ++j) mx = fmaxf(mx, sc[j]);
#pragma unroll
  for (int off = 16; off >= 1; off >>= 1) mx = fmaxf(mx, __shfl_xor(mx, off, 32));
  float ev[8]; float ssum = 0.f;
#pragma unroll
  for (int j = 0; j < 8; ++j) { ev[j] = expf(sc[j] - mx); ssum += ev[j]; }
#pragma unroll
  for (int off = 16; off >= 1; off >>= 1) ssum += __shfl_xor(ssum, off, 32);
  const float inv = 1.f / ssum;

  int msk = 0;
#pragma unroll
  for (int k = 0; k < TOPK; ++k) {
    float bv = -INFINITY; int bi = 1 << 30;
#pragma unroll
    for (int j = 0; j < 8; ++j) {
      if (!((msk >> j) & 1)) {
        const int gi = lane * 8 + j;
        if (sc[j] > bv || (sc[j] == bv && gi < bi)) { bv = sc[j]; bi = gi; }
      }
    }
    argmax32(bv, bi);
    if ((bi >> 3) == lane) msk |= 1 << (bi & 7);
    if (lane == k) {
      const int o = ((b * 256 + l) * TOPK + k) * NHEAD + h;
      tki0[o] = bi;
      tkp0[o] = expf(bv - mx) * inv;
    }
  }

#pragma unroll
  for (int j = 0; j < 8; ++j)
    probs[h][j * 32 + lane] = ((msk >> j) & 1) ? 0.f : ev[j] * inv;

  float acc = 0.f;
  const float* vrow = Vt + tb + h * 32 + lane;
#pragma unroll 8
  for (int s = 0; s < 256; ++s)
    acc += probs[h][((s & 7) << 5) | (s >> 3)] * vrow[(size_t)s * 256];

  msg0[((size_t)(b * 256 + l) * NHEAD + h) * DIM + lane] = acc;
}

// ---------------- Token-major refinement: rank topk + XCD-chunked swizzle --
// grid: B*(W/2)^2 blocks, 256 threads = 8 heads x 32 lanes (lane = entry e)
template <int W, bool HAS_TOPK>
__global__ __launch_bounds__(256) void refine_tm_kernel(
    const float* __restrict__ Qt, const float* __restrict__ Kt, const float* __restrict__ Vt,
    const float* __restrict__ msgp, const int* __restrict__ tkip, const float* __restrict__ tkpp,
    float* __restrict__ msgo, int* __restrict__ tkio, float* __restrict__ tkpo)
{
  constexpr int S  = W * W;
  constexpr int HW = W / 2;
  constexpr int Lp = HW * HW;
  constexpr int NWG = BATCH * Lp;      // % 8 == 0 -> bijective swizzle
  constexpr int PER = NWG / 8;
  const int bidx = (int)blockIdx.x;
  const int swz = (bidx & 7) * PER + (bidx >> 3);   // contiguous chunk per XCD
  const int b = swz / Lp;
  const int l = swz % Lp;
  const int gr = l / HW, gc = l % HW;
  const int t = threadIdx.x;
  const int h = t >> 5, lane = t & 31;

  __shared__ __align__(16) float q_s[NHEAD][4][DIM];
  __shared__ __align__(16) float w_s[NHEAD][32];
  __shared__ int cidx_s[NHEAD][32];

  const size_t tb = (size_t)b * S * 256;      // token-major [b,s,c]

  // entry e = lane: gathered child index + coarse score
  const int k0 = lane >> 2, f = lane & 3;
  const int pofs = ((b * Lp + l) * TOPK + k0) * NHEAD + h;
  const int ti = tkip[pofs];
  const float csc = tkpp[pofs];
  const int cidx = ((ti / HW) * 2 + (f >> 1)) * W + ((ti % HW) * 2 + (f & 1));
  cidx_s[h][lane] = cidx;
  // all LDS per-head within one half-wave (lockstep) -> no barriers

  // Q for the 4 fine children (coalesced)
#pragma unroll
  for (int wq = 0; wq < 4; ++wq) {
    const int rr = 2 * gr + (wq >> 1), cc = 2 * gc + (wq & 1);
    q_s[h][wq][lane] = Qt[tb + (size_t)(rr * W + cc) * 256 + h * DIM + lane];
  }

  const float mprev = msgp[((size_t)(b * Lp + l) * NHEAD + h) * DIM + lane];

  // K: per-lane float4 gather (lane = entry)
  float kv[DIM];
  {
    const float4* kp = (const float4*)(Kt + tb + (size_t)cidx * 256 + h * DIM);
#pragma unroll
    for (int j = 0; j < 8; ++j) {
      const float4 v4 = kp[j];
      kv[4 * j] = v4.x; kv[4 * j + 1] = v4.y; kv[4 * j + 2] = v4.z; kv[4 * j + 3] = v4.w;
    }
  }

  // V coalesced into registers: lane = dim, loop over entries
  float vv[32];
#pragma unroll
  for (int e = 0; e < 32; ++e)
    vv[e] = Vt[tb + (size_t)cidx_s[h][e] * 256 + h * DIM + lane];

  // qk for all 4 children (float4 broadcast reads of q_s)
  float qk4[4] = {0.f, 0.f, 0.f, 0.f};
#pragma unroll
  for (int d4 = 0; d4 < 8; ++d4) {
#pragma unroll
    for (int wq = 0; wq < 4; ++wq) {
      const float4 q4 = *(const float4*)&q_s[h][wq][d4 * 4];
      qk4[wq] += q4.x * kv[4 * d4] + q4.y * kv[4 * d4 + 1]
               + q4.z * kv[4 * d4 + 2] + q4.w * kv[4 * d4 + 3];
    }
  }

#pragma unroll
  for (int wq = 0; wq < 4; ++wq) {
    const float sval = TEMP * qk4[wq];

    // softmax over the 4 children (f groups of 4 lanes)
    float m1 = fmaxf(sval, __shfl_xor(sval, 1, 4));
    float m2 = fmaxf(m1, __shfl_xor(m1, 2, 4));
    float ex = expf(sval - m2);
    float s1 = ex + __shfl_xor(ex, 1, 4);
    float s2 = s1 + __shfl_xor(s1, 2, 4);
    const float A = (ex / s2) * csc;

    w_s[h][lane] = A;        // same-wave LDS ordering -> visible to reads below

    const int tok = (2 * gr + (wq >> 1)) * W + (2 * gc + (wq & 1));
    float acc = 0.f;

    if constexpr (HAS_TOPK) {
      // rank = # entries strictly ahead in jax.lax.top_k's stable descending order
      int rank = 0;
#pragma unroll
      for (int e4 = 0; e4 < 8; ++e4) {
        const float4 a4 = *(const float4*)&w_s[h][e4 * 4];
        rank += (a4.x > A || (a4.x == A && (e4 * 4 + 0) < lane));
        rank += (a4.y > A || (a4.y == A && (e4 * 4 + 1) < lane));
        rank += (a4.z > A || (a4.z == A && (e4 * 4 + 2) < lane));
        rank += (a4.w > A || (a4.w == A && (e4 * 4 + 3) < lane));
      }
      const unsigned long long bal = __ballot(rank < TOPK);
      const unsigned mbits = (unsigned)(bal >> (t & 32));  // this half-wave's 32 bits

      if (rank < TOPK) {
        const int o = ((b * S + tok) * TOPK + rank) * NHEAD + h;
        tkio[o] = cidx;
        tkpo[o] = A;
      }

      // PV with top-8 masked to zero (== reference's sum-minus-topk)
#pragma unroll
      for (int e4 = 0; e4 < 8; ++e4) {
        const float4 a4 = *(const float4*)&w_s[h][e4 * 4];
        acc += (((mbits >> (e4 * 4 + 0)) & 1) ? 0.f : a4.x) * vv[e4 * 4 + 0];
        acc += (((mbits >> (e4 * 4 + 1)) & 1) ? 0.f : a4.y) * vv[e4 * 4 + 1];
        acc += (((mbits >> (e4 * 4 + 2)) & 1) ? 0.f : a4.z) * vv[e4 * 4 + 2];
        acc += (((mbits >> (e4 * 4 + 3)) & 1) ? 0.f : a4.w) * vv[e4 * 4 + 3];
      }
    } else {
      // final level: plain weighted sum, no mask, no rank
#pragma unroll
      for (int e4 = 0; e4 < 8; ++e4) {
        const float4 a4 = *(const float4*)&w_s[h][e4 * 4];
        acc += a4.x * vv[e4 * 4 + 0];
        acc += a4.y * vv[e4 * 4 + 1];
        acc += a4.z * vv[e4 * 4 + 2];
        acc += a4.w * vv[e4 * 4 + 3];
      }
    }

    msgo[((size_t)(b * S + tok) * NHEAD + h) * DIM + lane] = mprev + acc;
  }
}

// ---------------- Fallback path (channel-major, small workspace) -----------
__global__ __launch_bounds__(256) void l0_cm_kernel(
    const float* __restrict__ Q, const float* __restrict__ K, const float* __restrict__ V,
    float* __restrict__ msg0, int* __restrict__ tki0, float* __restrict__ tkp0)
{
  const int b = blockIdx.x >> 8;
  const int l = blockIdx.x & 255;
  const int t = threadIdx.x;
  const int h = t >> 5, lane = t & 31;

  __shared__ float q_s[NHEAD][DIM];
  __shared__ float probs[NHEAD][256];

  const size_t cb = ((size_t)(b * 256 + h * 32)) * 256;
  q_s[h][lane] = Q[cb + (size_t)lane * 256 + l];

  float sc[8];
#pragma unroll
  for (int j = 0; j < 8; ++j) sc[j] = 0.f;
  for (int d = 0; d < 32; ++d) {
    const float qd = q_s[h][d];
    const float* kr = K + cb + (size_t)d * 256;
#pragma unroll
    for (int j = 0; j < 8; ++j) sc[j] += qd * kr[j * 32 + lane];
  }
#pragma unroll
  for (int j = 0; j < 8; ++j) sc[j] *= TEMP;

  float mx = sc[0];
#pragma unroll
  for (int j = 1; j < 8; ++j) mx = fmaxf(mx, sc[j]);
#pragma unroll
  for (int off = 16; off >= 1; off >>= 1) mx = fmaxf(mx, __shfl_xor(mx, off, 32));
  float ev[8]; float ssum = 0.f;
#pragma unroll
  for (int j = 0; j < 8; ++j) { ev[j] = expf(sc[j] - mx); ssum += ev[j]; }
#pragma unroll
  for (int off = 16; off >= 1; off >>= 1) ssum += __shfl_xor(ssum, off, 32);
  const float inv = 1.f / ssum;

  int msk = 0;
#pragma unroll
  for (int k = 0; k < TOPK; ++k) {
    float bv = -INFINITY; int bi = 1 << 30;
#pragma unroll
    for (int j = 0; j < 8; ++j) {
      if (!((msk >> j) & 1)) {
        int gi = j * 32 + lane;
        if (sc[j] > bv || (sc[j] == bv && gi < bi)) { bv = sc[j]; bi = gi; }
      }
    }
    argmax32(bv, bi);
    if ((bi & 31) == lane) msk |= 1 << (bi >> 5);
    if (lane == k) {
      const int o = ((b * 256 + l) * TOPK + k) * NHEAD + h;
      tki0[o] = bi;
      tkp0[o] = expf(bv - mx) * inv;
    }
  }

#pragma unroll
  for (int j = 0; j < 8; ++j)
    probs[h][j * 32 + lane] = ((msk >> j) & 1) ? 0.f : ev[j] * inv;
  __syncthreads();

  float acc = 0.f;
  const float* vr = V + cb + (size_t)lane * 256;
  for (int s = 0; s < 256; ++s) acc += probs[h][s] * vr[s];

  msg0[((size_t)(b * 256 + l) * NHEAD + h) * DIM + lane] = acc;
}

template <int W, bool HAS_TOPK>
__global__ __launch_bounds__(256) void refine_cm_kernel(
    const float* __restrict__ Q, const float* __restrict__ K, const float* __restrict__ V,
    const float* __restrict__ msgp, const int* __restrict__ tkip, const float* __restrict__ tkpp,
    float* __restrict__ msgo, int* __restrict__ tkio, float* __restrict__ tkpo)
{
  constexpr int S  = W * W;
  constexpr int HW = W / 2;
  constexpr int Lp = HW * HW;
  const int b = blockIdx.x / Lp;
  const int l = blockIdx.x % Lp;
  const int gr = l / HW, gc = l % HW;
  const int t = threadIdx.x;
  const int h = t >> 5, lane = t & 31;

  __shared__ float q_s[4][NHEAD][DIM];
  __shared__ int   cidx_s[NHEAD][32];
  __shared__ float w_s[NHEAD][32];

  const size_t cbase = ((size_t)(b * 256 + h * 32)) * S;

#pragma unroll
  for (int wq = 0; wq < 4; ++wq) {
    const int rr = 2 * gr + (wq >> 1), cc = 2 * gc + (wq & 1);
    q_s[wq][h][lane] = Q[cbase + (size_t)lane * S + rr * W + cc];
  }

  const int k0 = lane >> 2, f = lane & 3;
  const int pofs = ((b * Lp + l) * TOPK + k0) * NHEAD + h;
  const int ti = tkip[pofs];
  const float csc = tkpp[pofs];
  cidx_s[h][lane] = ((ti / HW) * 2 + (f >> 1)) * W + ((ti % HW) * 2 + (f & 1));
  const int cidx = cidx_s[h][lane];

  float kv[DIM];
#pragma unroll
  for (int d = 0; d < DIM; ++d) kv[d] = K[cbase + (size_t)d * S + cidx];

  const float mprev = msgp[((size_t)(b * Lp + l) * NHEAD + h) * DIM + lane];

  for (int wq = 0; wq < 4; ++wq) {
    float qk = 0.f;
#pragma unroll
    for (int d = 0; d < DIM; ++d) qk += q_s[wq][h][d] * kv[d];
    const float v = TEMP * qk;

    float m1 = fmaxf(v, __shfl_xor(v, 1, 4));
    float m2 = fmaxf(m1, __shfl_xor(m1, 2, 4));
    float ex = expf(v - m2);
    float s1 = ex + __shfl_xor(ex, 1, 4);
    float s2 = s1 + __shfl_xor(s1, 2, 4);
    const float A = (ex / s2) * csc;

    float Am = A;
    int   my_e = 0; float my_v = 0.f;
    if constexpr (HAS_TOPK) {
      bool mymask = false;
#pragma unroll
      for (int k = 0; k < TOPK; ++k) {
        float bv = mymask ? -INFINITY : A;
        int bi = lane;
        argmax32(bv, bi);
        if (bi == lane) mymask = true;
        if (lane == k) { my_e = bi; my_v = bv; }
      }
      if (mymask) Am = 0.f;
    }

    w_s[h][lane] = Am;

    float acc = 0.f;
    const float* vcol = V + cbase + (size_t)lane * S;
#pragma unroll
    for (int e = 0; e < 32; ++e) acc += w_s[h][e] * vcol[cidx_s[h][e]];
    const float outv = mprev + acc;

    const int rr = 2 * gr + (wq >> 1), cc = 2 * gc + (wq & 1);
    const int tok = rr * W + cc;
    msgo[((size_t)(b * S + tok) * NHEAD + h) * DIM + lane] = outv;
    if constexpr (HAS_TOPK) {
      if (lane < TOPK) {
        const int o = ((b * S + tok) * TOPK + lane) * NHEAD + h;
        tkio[o] = cidx_s[h][my_e];
        tkpo[o] = my_v;
      }
    }
  }
}

extern "C" void kernel_launch(void* const* d_in, const int* in_sizes, int n_in,
                              void* d_out, int out_size, void* d_ws, size_t ws_size,
                              hipStream_t stream)
{
  const float* Q0 = (const float*)d_in[0];  // 64x64 (fine)
  const float* Q1 = (const float*)d_in[1];  // 32x32
  const float* Q2 = (const float*)d_in[2];  // 16x16 (coarse)
  const float* K0 = (const float*)d_in[3];
  const float* K1 = (const float*)d_in[4];
  const float* K2 = (const float*)d_in[5];
  const float* V0 = (const float*)d_in[6];
  const float* V1 = (const float*)d_in[7];
  const float* V2 = (const float*)d_in[8];
  float* out = (float*)d_out;

  const size_t N_MSG0 = (size_t)BATCH * 256 * NHEAD * DIM;
  const size_t N_TK0  = (size_t)BATCH * 256 * TOPK * NHEAD;
  const size_t N_MSG1 = (size_t)BATCH * 1024 * NHEAD * DIM;
  const size_t N_TK1  = (size_t)BATCH * 1024 * TOPK * NHEAD;
  const size_t N_T2   = (size_t)BATCH * 256 * 256;
  const size_t N_T1   = (size_t)BATCH * 1024 * 256;
  const size_t N_T0   = (size_t)BATCH * 4096 * 256;

  float* p = (float*)d_ws;
  float* msg0 = p;            p += N_MSG0;
  int*   tki0 = (int*)p;      p += N_TK0;
  float* tkp0 = p;            p += N_TK0;
  float* msg1 = p;            p += N_MSG1;
  int*   tki1 = (int*)p;      p += N_TK1;
  float* tkp1 = p;            p += N_TK1;
  float* Vt2  = p;            p += N_T2;
  float* Qt1  = p;            p += N_T1;
  float* Kt1  = p;            p += N_T1;
  float* Vt1  = p;            p += N_T1;
  float* Qt0  = p;            p += N_T0;
  float* Kt0  = p;            p += N_T0;
  float* Vt0  = p;            p += N_T0;
  const size_t need_bytes = (size_t)(p - (float*)d_ws) * sizeof(float);

  if (ws_size >= need_bytes) {
    hipLaunchKernelGGL(transpose_all, dim3(256 + 3072 + 12288), dim3(256), 0, stream,
                       V2, Vt2, Q1, K1, V1, Qt1, Kt1, Vt1, Q0, K0, V0, Qt0, Kt0, Vt0);
    hipLaunchKernelGGL(l0_kernel_v4, dim3(BATCH * 256), dim3(256), 0, stream,
                       Q2, K2, Vt2, msg0, tki0, tkp0);
    hipLaunchKernelGGL((refine_tm_kernel<32, true>), dim3(BATCH * 256), dim3(256), 0, stream,
                       Qt1, Kt1, Vt1, msg0, tki0, tkp0, msg1, tki1, tkp1);
    hipLaunchKernelGGL((refine_tm_kernel<64, false>), dim3(BATCH * 1024), dim3(256), 0, stream,
                       Qt0, Kt0, Vt0, msg1, tki1, tkp1, out, nullptr, nullptr);
  } else {
    hipLaunchKernelGGL(l0_cm_kernel, dim3(BATCH * 256), dim3(256), 0, stream,
                       Q2, K2, V2, msg0, tki0, tkp0);
    hipLaunchKernelGGL((refine_cm_kernel<32, true>), dim3(BATCH * 256), dim3(256), 0, stream,
                       Q1, K1, V1, msg0, tki0, tkp0, msg1, tki1, tkp1);
    hipLaunchKernelGGL((refine_cm_kernel<64, false>), dim3(BATCH * 1024), dim3(256), 0, stream,
                       Q0, K0, V0, msg1, tki1, tkp1, out, nullptr, nullptr);
  }
}

// Round 10
// 104.786 us; speedup vs baseline: 1.2965x; 1.0982x over previous
//
#include <hip/hip_runtime.h>
#include <math.h>

#define NHEAD 8
#define DIM   32
#define TOPK  8
#define TEMP  0.17677669529663687f   // 1/sqrt(32)
#define BATCH 4

// Butterfly argmax over 32 lanes, tie-break: lowest index (matches jax.lax.top_k)
__device__ __forceinline__ void argmax32(float& v, int& i) {
#pragma unroll
  for (int off = 16; off >= 1; off >>= 1) {
    float ov = __shfl_xor(v, off, 32);
    int   oi = __shfl_xor(i, off, 32);
    if (ov > v || (ov == v && oi < i)) { v = ov; i = oi; }
  }
}

// ---------------- Merged kernel: l0 attention (blocks 0..1023) +
//                  transposes lvl1/lvl0 (blocks 1024..16383) ----------------
// l0: one block per (b, coarse token); 8 heads x 32 lanes; lane owns s=lane*8+j.
// PV goes through channel-major V2 with an LDS-staged padded transpose, so
// l0 has NO dependency on the transpose outputs -> both roles run concurrently.
__global__ __launch_bounds__(256) void l0_plus_transpose(
    const float* __restrict__ Q2, const float* __restrict__ K2, const float* __restrict__ V2,
    float* __restrict__ msg0, int* __restrict__ tki0, float* __restrict__ tkp0,
    const float* __restrict__ Q1, const float* __restrict__ K1, const float* __restrict__ V1,
    float* __restrict__ Qt1, float* __restrict__ Kt1, float* __restrict__ Vt1,
    const float* __restrict__ Q0, const float* __restrict__ K0, const float* __restrict__ V0,
    float* __restrict__ Qt0, float* __restrict__ Kt0, float* __restrict__ Vt0)
{
  // pool: l0 uses q_s (8*32) + plds (8*32*33); transpose uses tile[32][36]
  __shared__ float lds_pool[256 + NHEAD * 32 * 33];

  if (blockIdx.x >= 1024) {
    // ---------------- transpose role ----------------
    int id = blockIdx.x - 1024;
    const float* in; float* out; int S, b, t;
    if (id < 3072) {                      // level1 Q,K,V (S=1024)
      S = 1024;
      const int tsel = id >> 10;
      in  = tsel == 0 ? Q1 : tsel == 1 ? K1 : V1;
      out = tsel == 0 ? Qt1 : tsel == 1 ? Kt1 : Vt1;
      b = (id >> 8) & 3; t = id & 255;
    } else {                              // level0 Q,K,V (S=4096)
      id -= 3072; S = 4096;
      const int tsel = id >> 12;
      in  = tsel == 0 ? Q0 : tsel == 1 ? K0 : V0;
      out = tsel == 0 ? Qt0 : tsel == 1 ? Kt0 : Vt0;
      b = (id >> 10) & 3; t = id & 1023;
    }
    float (*tile)[36] = (float(*)[36])lds_pool;
    const int sx = t / 8, cy = t % 8;
    const int s0 = sx * 32, c0 = cy * 32;
    const int tid = threadIdx.x;
    const int i = tid >> 3, c4 = tid & 7;

    const float4 v4 = *(const float4*)(in + ((size_t)b * 256 + c0 + i) * S + s0 + c4 * 4);
    *(float4*)&tile[i][c4 * 4] = v4;
    __syncthreads();
    float4 w;
    w.x = tile[c4 * 4 + 0][i];
    w.y = tile[c4 * 4 + 1][i];
    w.z = tile[c4 * 4 + 2][i];
    w.w = tile[c4 * 4 + 3][i];
    *(float4*)(out + ((size_t)b * S + s0 + i) * 256 + c0 + c4 * 4) = w;
    return;
  }

  // ---------------- l0 role ----------------
  const int b = blockIdx.x >> 8;
  const int l = blockIdx.x & 255;
  const int t = threadIdx.x;
  const int h = t >> 5, lane = t & 31;

  float* q_s  = lds_pool + h * 32;                 // per-head, half-wave local
  float* plds = lds_pool + 256 + h * (32 * 33);    // padded transpose buffer

  const size_t cb = ((size_t)(b * 256 + h * 32)) * 256;  // channel-major [b,c,s]

  q_s[lane] = Q2[cb + (size_t)lane * 256 + l];
  // same half-wave writes/reads -> in-order LDS, no barrier

  float sc[8];
#pragma unroll
  for (int j = 0; j < 8; ++j) sc[j] = 0.f;
  const float* kbase = K2 + cb + lane * 8;
  for (int d = 0; d < 32; ++d) {
    const float4 ka = *(const float4*)(kbase + (size_t)d * 256);
    const float4 kb = *(const float4*)(kbase + (size_t)d * 256 + 4);
    const float qd = q_s[d];
    sc[0] += qd * ka.x; sc[1] += qd * ka.y; sc[2] += qd * ka.z; sc[3] += qd * ka.w;
    sc[4] += qd * kb.x; sc[5] += qd * kb.y; sc[6] += qd * kb.z; sc[7] += qd * kb.w;
  }
#pragma unroll
  for (int j = 0; j < 8; ++j) sc[j] *= TEMP;

  // softmax over all 256
  float mx = sc[0];
#pragma unroll
  for (int j = 1; j < 8; ++j) mx = fmaxf(mx, sc[j]);
#pragma unroll
  for (int off = 16; off >= 1; off >>= 1) mx = fmaxf(mx, __shfl_xor(mx, off, 32));
  float ev[8]; float ssum = 0.f;
#pragma unroll
  for (int j = 0; j < 8; ++j) { ev[j] = expf(sc[j] - mx); ssum += ev[j]; }
#pragma unroll
  for (int off = 16; off >= 1; off >>= 1) ssum += __shfl_xor(ssum, off, 32);
  const float inv = 1.f / ssum;

  // top-8 on scaled scores; global id gi = lane*8+j
  int msk = 0;
#pragma unroll
  for (int k = 0; k < TOPK; ++k) {
    float bv = -INFINITY; int bi = 1 << 30;
#pragma unroll
    for (int j = 0; j < 8; ++j) {
      if (!((msk >> j) & 1)) {
        const int gi = lane * 8 + j;
        if (sc[j] > bv || (sc[j] == bv && gi < bi)) { bv = sc[j]; bi = gi; }
      }
    }
    argmax32(bv, bi);
    if ((bi >> 3) == lane) msk |= 1 << (bi & 7);
    if (lane == k) {
      const int o = ((b * 256 + l) * TOPK + k) * NHEAD + h;
      tki0[o] = bi;
      tkp0[o] = expf(bv - mx) * inv;
    }
  }

  // masked probabilities stay in registers (lane owns s = lane*8+j)
  float p[8];
#pragma unroll
  for (int j = 0; j < 8; ++j) p[j] = ((msk >> j) & 1) ? 0.f : ev[j] * inv;

  // PV via LDS-staged transpose: for each dim d, lane contributes its 8 tokens'
  // partial, written to padded plds[d*33+lane] (conflict-free both phases).
  const float* vb = V2 + cb + lane * 8;
#pragma unroll
  for (int d = 0; d < 32; ++d) {
    const float4 va = *(const float4*)(vb + (size_t)d * 256);
    const float4 vq = *(const float4*)(vb + (size_t)d * 256 + 4);
    plds[d * 33 + lane] =
        p[0] * va.x + p[1] * va.y + p[2] * va.z + p[3] * va.w
      + p[4] * vq.x + p[5] * vq.y + p[6] * vq.z + p[7] * vq.w;
  }
  // lane = output dim d: sum the 32 per-lane partials (same half-wave, in-order)
  float acc = 0.f;
#pragma unroll
  for (int e = 0; e < 32; ++e) acc += plds[lane * 33 + e];

  msg0[((size_t)(b * 256 + l) * NHEAD + h) * DIM + lane] = acc;
}

// ---------------- Token-major refinement: rank topk + XCD-chunked swizzle --
// grid: B*(W/2)^2 blocks, 256 threads = 8 heads x 32 lanes (lane = entry e)
template <int W, bool HAS_TOPK>
__global__ __launch_bounds__(256) void refine_tm_kernel(
    const float* __restrict__ Qt, const float* __restrict__ Kt, const float* __restrict__ Vt,
    const float* __restrict__ msgp, const int* __restrict__ tkip, const float* __restrict__ tkpp,
    float* __restrict__ msgo, int* __restrict__ tkio, float* __restrict__ tkpo)
{
  constexpr int S  = W * W;
  constexpr int HW = W / 2;
  constexpr int Lp = HW * HW;
  constexpr int NWG = BATCH * Lp;      // % 8 == 0 -> bijective swizzle
  constexpr int PER = NWG / 8;
  const int bidx = (int)blockIdx.x;
  const int swz = (bidx & 7) * PER + (bidx >> 3);   // contiguous chunk per XCD
  const int b = swz / Lp;
  const int l = swz % Lp;
  const int gr = l / HW, gc = l % HW;
  const int t = threadIdx.x;
  const int h = t >> 5, lane = t & 31;

  __shared__ __align__(16) float q_s[NHEAD][4][DIM];
  __shared__ __align__(16) float w_s[NHEAD][32];
  __shared__ int cidx_s[NHEAD][32];

  const size_t tb = (size_t)b * S * 256;      // token-major [b,s,c]

  // entry e = lane: gathered child index + coarse score
  const int k0 = lane >> 2, f = lane & 3;
  const int pofs = ((b * Lp + l) * TOPK + k0) * NHEAD + h;
  const int ti = tkip[pofs];
  const float csc = tkpp[pofs];
  const int cidx = ((ti / HW) * 2 + (f >> 1)) * W + ((ti % HW) * 2 + (f & 1));
  cidx_s[h][lane] = cidx;
  // all LDS per-head within one half-wave (lockstep) -> no barriers

  // Q for the 4 fine children (coalesced)
#pragma unroll
  for (int wq = 0; wq < 4; ++wq) {
    const int rr = 2 * gr + (wq >> 1), cc = 2 * gc + (wq & 1);
    q_s[h][wq][lane] = Qt[tb + (size_t)(rr * W + cc) * 256 + h * DIM + lane];
  }

  const float mprev = msgp[((size_t)(b * Lp + l) * NHEAD + h) * DIM + lane];

  // K: per-lane float4 gather (lane = entry)
  float kv[DIM];
  {
    const float4* kp = (const float4*)(Kt + tb + (size_t)cidx * 256 + h * DIM);
#pragma unroll
    for (int j = 0; j < 8; ++j) {
      const float4 v4 = kp[j];
      kv[4 * j] = v4.x; kv[4 * j + 1] = v4.y; kv[4 * j + 2] = v4.z; kv[4 * j + 3] = v4.w;
    }
  }

  // V coalesced into registers: lane = dim, loop over entries
  float vv[32];
#pragma unroll
  for (int e = 0; e < 32; ++e)
    vv[e] = Vt[tb + (size_t)cidx_s[h][e] * 256 + h * DIM + lane];

  // qk for all 4 children (float4 broadcast reads of q_s)
  float qk4[4] = {0.f, 0.f, 0.f, 0.f};
#pragma unroll
  for (int d4 = 0; d4 < 8; ++d4) {
#pragma unroll
    for (int wq = 0; wq < 4; ++wq) {
      const float4 q4 = *(const float4*)&q_s[h][wq][d4 * 4];
      qk4[wq] += q4.x * kv[4 * d4] + q4.y * kv[4 * d4 + 1]
               + q4.z * kv[4 * d4 + 2] + q4.w * kv[4 * d4 + 3];
    }
  }

#pragma unroll
  for (int wq = 0; wq < 4; ++wq) {
    const float sval = TEMP * qk4[wq];

    // softmax over the 4 children (f groups of 4 lanes)
    float m1 = fmaxf(sval, __shfl_xor(sval, 1, 4));
    float m2 = fmaxf(m1, __shfl_xor(m1, 2, 4));
    float ex = expf(sval - m2);
    float s1 = ex + __shfl_xor(ex, 1, 4);
    float s2 = s1 + __shfl_xor(s1, 2, 4);
    const float A = (ex / s2) * csc;

    w_s[h][lane] = A;        // same-wave LDS ordering -> visible to reads below

    const int tok = (2 * gr + (wq >> 1)) * W + (2 * gc + (wq & 1));
    float acc = 0.f;

    if constexpr (HAS_TOPK) {
      // rank = # entries strictly ahead in jax.lax.top_k's stable descending order
      int rank = 0;
#pragma unroll
      for (int e4 = 0; e4 < 8; ++e4) {
        const float4 a4 = *(const float4*)&w_s[h][e4 * 4];
        rank += (a4.x > A || (a4.x == A && (e4 * 4 + 0) < lane));
        rank += (a4.y > A || (a4.y == A && (e4 * 4 + 1) < lane));
        rank += (a4.z > A || (a4.z == A && (e4 * 4 + 2) < lane));
        rank += (a4.w > A || (a4.w == A && (e4 * 4 + 3) < lane));
      }
      const unsigned long long bal = __ballot(rank < TOPK);
      const unsigned mbits = (unsigned)(bal >> (t & 32));  // this half-wave's 32 bits

      if (rank < TOPK) {
        const int o = ((b * S + tok) * TOPK + rank) * NHEAD + h;
        tkio[o] = cidx;
        tkpo[o] = A;
      }

      // PV with top-8 masked to zero (== reference's sum-minus-topk)
#pragma unroll
      for (int e4 = 0; e4 < 8; ++e4) {
        const float4 a4 = *(const float4*)&w_s[h][e4 * 4];
        acc += (((mbits >> (e4 * 4 + 0)) & 1) ? 0.f : a4.x) * vv[e4 * 4 + 0];
        acc += (((mbits >> (e4 * 4 + 1)) & 1) ? 0.f : a4.y) * vv[e4 * 4 + 1];
        acc += (((mbits >> (e4 * 4 + 2)) & 1) ? 0.f : a4.z) * vv[e4 * 4 + 2];
        acc += (((mbits >> (e4 * 4 + 3)) & 1) ? 0.f : a4.w) * vv[e4 * 4 + 3];
      }
    } else {
      // final level: plain weighted sum, no mask, no rank
#pragma unroll
      for (int e4 = 0; e4 < 8; ++e4) {
        const float4 a4 = *(const float4*)&w_s[h][e4 * 4];
        acc += a4.x * vv[e4 * 4 + 0];
        acc += a4.y * vv[e4 * 4 + 1];
        acc += a4.z * vv[e4 * 4 + 2];
        acc += a4.w * vv[e4 * 4 + 3];
      }
    }

    msgo[((size_t)(b * S + tok) * NHEAD + h) * DIM + lane] = mprev + acc;
  }
}

// ---------------- Fallback path (channel-major, small workspace) -----------
__global__ __launch_bounds__(256) void l0_cm_kernel(
    const float* __restrict__ Q, const float* __restrict__ K, const float* __restrict__ V,
    float* __restrict__ msg0, int* __restrict__ tki0, float* __restrict__ tkp0)
{
  const int b = blockIdx.x >> 8;
  const int l = blockIdx.x & 255;
  const int t = threadIdx.x;
  const int h = t >> 5, lane = t & 31;

  __shared__ float q_s[NHEAD][DIM];
  __shared__ float probs[NHEAD][256];

  const size_t cb = ((size_t)(b * 256 + h * 32)) * 256;
  q_s[h][lane] = Q[cb + (size_t)lane * 256 + l];

  float sc[8];
#pragma unroll
  for (int j = 0; j < 8; ++j) sc[j] = 0.f;
  for (int d = 0; d < 32; ++d) {
    const float qd = q_s[h][d];
    const float* kr = K + cb + (size_t)d * 256;
#pragma unroll
    for (int j = 0; j < 8; ++j) sc[j] += qd * kr[j * 32 + lane];
  }
#pragma unroll
  for (int j = 0; j < 8; ++j) sc[j] *= TEMP;

  float mx = sc[0];
#pragma unroll
  for (int j = 1; j < 8; ++j) mx = fmaxf(mx, sc[j]);
#pragma unroll
  for (int off = 16; off >= 1; off >>= 1) mx = fmaxf(mx, __shfl_xor(mx, off, 32));
  float ev[8]; float ssum = 0.f;
#pragma unroll
  for (int j = 0; j < 8; ++j) { ev[j] = expf(sc[j] - mx); ssum += ev[j]; }
#pragma unroll
  for (int off = 16; off >= 1; off >>= 1) ssum += __shfl_xor(ssum, off, 32);
  const float inv = 1.f / ssum;

  int msk = 0;
#pragma unroll
  for (int k = 0; k < TOPK; ++k) {
    float bv = -INFINITY; int bi = 1 << 30;
#pragma unroll
    for (int j = 0; j < 8; ++j) {
      if (!((msk >> j) & 1)) {
        int gi = j * 32 + lane;
        if (sc[j] > bv || (sc[j] == bv && gi < bi)) { bv = sc[j]; bi = gi; }
      }
    }
    argmax32(bv, bi);
    if ((bi & 31) == lane) msk |= 1 << (bi >> 5);
    if (lane == k) {
      const int o = ((b * 256 + l) * TOPK + k) * NHEAD + h;
      tki0[o] = bi;
      tkp0[o] = expf(bv - mx) * inv;
    }
  }

#pragma unroll
  for (int j = 0; j < 8; ++j)
    probs[h][j * 32 + lane] = ((msk >> j) & 1) ? 0.f : ev[j] * inv;
  __syncthreads();

  float acc = 0.f;
  const float* vr = V + cb + (size_t)lane * 256;
  for (int s = 0; s < 256; ++s) acc += probs[h][s] * vr[s];

  msg0[((size_t)(b * 256 + l) * NHEAD + h) * DIM + lane] = acc;
}

template <int W, bool HAS_TOPK>
__global__ __launch_bounds__(256) void refine_cm_kernel(
    const float* __restrict__ Q, const float* __restrict__ K, const float* __restrict__ V,
    const float* __restrict__ msgp, const int* __restrict__ tkip, const float* __restrict__ tkpp,
    float* __restrict__ msgo, int* __restrict__ tkio, float* __restrict__ tkpo)
{
  constexpr int S  = W * W;
  constexpr int HW = W / 2;
  constexpr int Lp = HW * HW;
  const int b = blockIdx.x / Lp;
  const int l = blockIdx.x % Lp;
  const int gr = l / HW, gc = l % HW;
  const int t = threadIdx.x;
  const int h = t >> 5, lane = t & 31;

  __shared__ float q_s[4][NHEAD][DIM];
  __shared__ int   cidx_s[NHEAD][32];
  __shared__ float w_s[NHEAD][32];

  const size_t cbase = ((size_t)(b * 256 + h * 32)) * S;

#pragma unroll
  for (int wq = 0; wq < 4; ++wq) {
    const int rr = 2 * gr + (wq >> 1), cc = 2 * gc + (wq & 1);
    q_s[wq][h][lane] = Q[cbase + (size_t)lane * S + rr * W + cc];
  }

  const int k0 = lane >> 2, f = lane & 3;
  const int pofs = ((b * Lp + l) * TOPK + k0) * NHEAD + h;
  const int ti = tkip[pofs];
  const float csc = tkpp[pofs];
  cidx_s[h][lane] = ((ti / HW) * 2 + (f >> 1)) * W + ((ti % HW) * 2 + (f & 1));
  const int cidx = cidx_s[h][lane];

  float kv[DIM];
#pragma unroll
  for (int d = 0; d < DIM; ++d) kv[d] = K[cbase + (size_t)d * S + cidx];

  const float mprev = msgp[((size_t)(b * Lp + l) * NHEAD + h) * DIM + lane];

  for (int wq = 0; wq < 4; ++wq) {
    float qk = 0.f;
#pragma unroll
    for (int d = 0; d < DIM; ++d) qk += q_s[wq][h][d] * kv[d];
    const float v = TEMP * qk;

    float m1 = fmaxf(v, __shfl_xor(v, 1, 4));
    float m2 = fmaxf(m1, __shfl_xor(m1, 2, 4));
    float ex = expf(v - m2);
    float s1 = ex + __shfl_xor(ex, 1, 4);
    float s2 = s1 + __shfl_xor(s1, 2, 4);
    const float A = (ex / s2) * csc;

    float Am = A;
    int   my_e = 0; float my_v = 0.f;
    if constexpr (HAS_TOPK) {
      bool mymask = false;
#pragma unroll
      for (int k = 0; k < TOPK; ++k) {
        float bv = mymask ? -INFINITY : A;
        int bi = lane;
        argmax32(bv, bi);
        if (bi == lane) mymask = true;
        if (lane == k) { my_e = bi; my_v = bv; }
      }
      if (mymask) Am = 0.f;
    }

    w_s[h][lane] = Am;

    float acc = 0.f;
    const float* vcol = V + cbase + (size_t)lane * S;
#pragma unroll
    for (int e = 0; e < 32; ++e) acc += w_s[h][e] * vcol[cidx_s[h][e]];
    const float outv = mprev + acc;

    const int rr = 2 * gr + (wq >> 1), cc = 2 * gc + (wq & 1);
    const int tok = rr * W + cc;
    msgo[((size_t)(b * S + tok) * NHEAD + h) * DIM + lane] = outv;
    if constexpr (HAS_TOPK) {
      if (lane < TOPK) {
        const int o = ((b * S + tok) * TOPK + lane) * NHEAD + h;
        tkio[o] = cidx_s[h][my_e];
        tkpo[o] = my_v;
      }
    }
  }
}

extern "C" void kernel_launch(void* const* d_in, const int* in_sizes, int n_in,
                              void* d_out, int out_size, void* d_ws, size_t ws_size,
                              hipStream_t stream)
{
  const float* Q0 = (const float*)d_in[0];  // 64x64 (fine)
  const float* Q1 = (const float*)d_in[1];  // 32x32
  const float* Q2 = (const float*)d_in[2];  // 16x16 (coarse)
  const float* K0 = (const float*)d_in[3];
  const float* K1 = (const float*)d_in[4];
  const float* K2 = (const float*)d_in[5];
  const float* V0 = (const float*)d_in[6];
  const float* V1 = (const float*)d_in[7];
  const float* V2 = (const float*)d_in[8];
  float* out = (float*)d_out;

  const size_t N_MSG0 = (size_t)BATCH * 256 * NHEAD * DIM;
  const size_t N_TK0  = (size_t)BATCH * 256 * TOPK * NHEAD;
  const size_t N_MSG1 = (size_t)BATCH * 1024 * NHEAD * DIM;
  const size_t N_TK1  = (size_t)BATCH * 1024 * TOPK * NHEAD;
  const size_t N_T1   = (size_t)BATCH * 1024 * 256;
  const size_t N_T0   = (size_t)BATCH * 4096 * 256;

  float* p = (float*)d_ws;
  float* msg0 = p;            p += N_MSG0;
  int*   tki0 = (int*)p;      p += N_TK0;
  float* tkp0 = p;            p += N_TK0;
  float* msg1 = p;            p += N_MSG1;
  int*   tki1 = (int*)p;      p += N_TK1;
  float* tkp1 = p;            p += N_TK1;
  float* Qt1  = p;            p += N_T1;
  float* Kt1  = p;            p += N_T1;
  float* Vt1  = p;            p += N_T1;
  float* Qt0  = p;            p += N_T0;
  float* Kt0  = p;            p += N_T0;
  float* Vt0  = p;            p += N_T0;
  const size_t need_bytes = (size_t)(p - (float*)d_ws) * sizeof(float);

  if (ws_size >= need_bytes) {
    hipLaunchKernelGGL(l0_plus_transpose, dim3(1024 + 3072 + 12288), dim3(256), 0, stream,
                       Q2, K2, V2, msg0, tki0, tkp0,
                       Q1, K1, V1, Qt1, Kt1, Vt1,
                       Q0, K0, V0, Qt0, Kt0, Vt0);
    hipLaunchKernelGGL((refine_tm_kernel<32, true>), dim3(BATCH * 256), dim3(256), 0, stream,
                       Qt1, Kt1, Vt1, msg0, tki0, tkp0, msg1, tki1, tkp1);
    hipLaunchKernelGGL((refine_tm_kernel<64, false>), dim3(BATCH * 1024), dim3(256), 0, stream,
                       Qt0, Kt0, Vt0, msg1, tki1, tkp1, out, nullptr, nullptr);
  } else {
    hipLaunchKernelGGL(l0_cm_kernel, dim3(BATCH * 256), dim3(256), 0, stream,
                       Q2, K2, V2, msg0, tki0, tkp0);
    hipLaunchKernelGGL((refine_cm_kernel<32, true>), dim3(BATCH * 256), dim3(256), 0, stream,
                       Q1, K1, V1, msg0, tki0, tkp0, msg1, tki1, tkp1);
    hipLaunchKernelGGL((refine_cm_kernel<64, false>), dim3(BATCH * 1024), dim3(256), 0, stream,
                       Q0, K0, V0, msg1, tki1, tkp1, out, nullptr, nullptr);
  }
}